// Round 5
// baseline (559.976 us; speedup 1.0000x reference)
//
#include <hip/hip_runtime.h>

#define NBINS 15
#define RPI   64            // rows per block-iteration
#define PADF4 26            // padded row stride in float4 (25 data + 1 pad)

// LDS-STAGED STREAMING. Global loads are perfectly lane-consecutive float4
// (the m13 6.29 TB/s pattern): wave w stages rows [16w,16w+16) of the block's
// 64-row tile, lane reads float4 (64t+lane) of the wave's contiguous 6.4 KB
// chunk — every instruction is 1 KB of consecutive addresses. Rows are
// scattered into LDS padded to 26 float4 so the read phase (4 lanes/row,
// lane l reads float4 4j+l) aliases only 2-way (free). All per-row work
// (sum/sumsq/max+argmax, p[label] gather) then runs out of LDS.
__global__ __launch_bounds__(256) void ece_rows(const float* __restrict__ probs,
                                                const int* __restrict__ labels,
                                                int N,
                                                double* __restrict__ g_bri,
                                                float* __restrict__ g_cnt,
                                                float* __restrict__ g_conf,
                                                float* __restrict__ g_acc) {
    __shared__ float4 s_buf[RPI * PADF4];          // 26624 B
    __shared__ float  s_hist[3][RPI][NBINS];       // 11520 B, leader-private
    __shared__ float  s_bri;
    const int tid = threadIdx.x;
    for (int i = tid; i < 3 * RPI * NBINS; i += 256)
        ((float*)s_hist)[i] = 0.f;
    if (tid == 0) s_bri = 0.f;
    // (init is ordered before first use by the post-staging __syncthreads)

    const int lane = tid & 63;
    const int w    = tid >> 6;     // wave 0..3
    const int l    = tid & 3;      // sub-lane within 4-lane group
    const int grp  = tid >> 2;     // row-group 0..63
    float tbri = 0.f;

    const float4* g4 = (const float4*)probs;
    const int itersTotal = (N + RPI - 1) / RPI;

    for (int it = blockIdx.x; it < itersTotal; it += gridDim.x) {
        const int rbase = it * RPI;
        const int rows_here = min(RPI, N - rbase);

        // ---- stage: fully-coalesced global -> padded LDS
        if (rows_here == RPI) {
            const size_t gbase = (size_t)(rbase + 16 * w) * 25;
            #pragma unroll
            for (int t = 0; t < 6; t++) {
                int k = t * 64 + lane;             // float4 idx in wave chunk [0,400)
                float4 v = g4[gbase + k];
                int lr = k / 25, lp = k - lr * 25; // magic-mul, cheap
                s_buf[(16 * w + lr) * PADF4 + lp] = v;
            }
            if (lane < 16) {
                int k = 384 + lane;
                float4 v = g4[gbase + k];
                int lr = k / 25, lp = k - lr * 25;
                s_buf[(16 * w + lr) * PADF4 + lp] = v;
            }
        } else {                                    // guarded tail (never for N=1e6)
            for (int k = tid; k < rows_here * 25; k += 256) {
                float4 v = g4[(size_t)rbase * 25 + k];
                int lr = k / 25, lp = k - lr * 25;
                s_buf[lr * PADF4 + lp] = v;
            }
        }
        __syncthreads();

        // ---- reduce: 4 lanes per row, all from LDS
        const int r = rbase + grp;
        if (r < N) {
            const float4* rowb = &s_buf[grp * PADF4];
            float sum = 0.f, sq = 0.f, vmax = -1.f;
            int imax = 0;
            float4 v[6];
            #pragma unroll
            for (int j = 0; j < 6; j++) v[j] = rowb[4 * j + l];
            #pragma unroll
            for (int j = 0; j < 6; j++) {
                float4 u = v[j];
                int c = (4 * j + l) * 4;
                sum += (u.x + u.y) + (u.z + u.w);
                sq = fmaf(u.x, u.x, sq);
                sq = fmaf(u.y, u.y, sq);
                sq = fmaf(u.z, u.z, sq);
                sq = fmaf(u.w, u.w, sq);
                if (u.x > vmax) { vmax = u.x; imax = c; }
                if (u.y > vmax) { vmax = u.y; imax = c + 1; }
                if (u.z > vmax) { vmax = u.z; imax = c + 2; }
                if (u.w > vmax) { vmax = u.w; imax = c + 3; }
            }
            if (l == 0) {                           // float4 #24 (cols 96..99)
                float4 u = rowb[24];
                sum += (u.x + u.y) + (u.z + u.w);
                sq = fmaf(u.x, u.x, sq);
                sq = fmaf(u.y, u.y, sq);
                sq = fmaf(u.z, u.z, sq);
                sq = fmaf(u.w, u.w, sq);
                if (u.x > vmax) { vmax = u.x; imax = 96; }
                if (u.y > vmax) { vmax = u.y; imax = 97; }
                if (u.z > vmax) { vmax = u.z; imax = 98; }
                if (u.w > vmax) { vmax = u.w; imax = 99; }
            }
            #pragma unroll
            for (int off = 1; off <= 2; off <<= 1) {
                sum += __shfl_xor(sum, off);
                sq  += __shfl_xor(sq,  off);
                float ov = __shfl_xor(vmax, off);
                int   oi = __shfl_xor(imax, off);
                if (ov > vmax || (ov == vmax && oi < imax)) { vmax = ov; imax = oi; }
            }
            if (l == 0) {
                const int label = labels[r];
                const float pl = ((const float*)rowb)[label];   // LDS gather
                const float inv = 1.f / sum;
                const float conf = vmax * inv;    // softmax(log p) max == M/S
                const float acc = (imax == label) ? 1.f : 0.f;
                tbri += sq * inv * inv - 2.f * (pl * inv) + 1.f;
                int bin = (int)ceilf(conf * (float)NBINS) - 1;
                bin = bin < 0 ? 0 : (bin > NBINS - 1 ? NBINS - 1 : bin);
                s_hist[0][grp][bin] += 1.f;       // leader-private, no atomics
                s_hist[1][grp][bin] += conf;
                s_hist[2][grp][bin] += acc;
            }
        }
        __syncthreads();                           // WAR: s_buf reused next iter
    }

    // ---- brier wave-reduce (non-leaders carry 0), one LDS add per wave
    #pragma unroll
    for (int off = 32; off > 0; off >>= 1)
        tbri += __shfl_down(tbri, off);
    if (lane == 0) atomicAdd(&s_bri, tbri);
    __syncthreads();

    // ---- flush: 45 threads fold 64 leader histograms -> 1 global atomic each
    if (tid < 3 * NBINS) {
        const int a = tid / NBINS, b = tid % NBINS;
        float acc = 0.f;
        #pragma unroll
        for (int g = 0; g < RPI; g++) acc += s_hist[a][g][b];
        float* dst = (a == 0) ? g_cnt : (a == 1) ? g_conf : g_acc;
        atomicAdd(&dst[b], acc);
    }
    if (tid == 0) atomicAdd(g_bri, (double)s_bri);
}

__global__ void ece_final(const double* __restrict__ g_bri,
                          const float* __restrict__ g_cnt,
                          const float* __restrict__ g_conf,
                          const float* __restrict__ g_acc,
                          float* __restrict__ out, float invN) {
    if (threadIdx.x == 0 && blockIdx.x == 0) {
        float ece = 0.f, mx = 0.f;
        for (int b = 0; b < NBINS; b++) {
            float c = g_cnt[b];
            float gap = 0.f;
            if (c > 0.f) gap = fabsf(g_conf[b] / c - g_acc[b] / c);
            ece += gap * (c * invN);
            if (gap > mx) mx = gap;
        }
        out[0] = ece;
        out[1] = mx;
        out[2] = (float)(g_bri[0] * (double)invN);
    }
}

extern "C" void kernel_launch(void* const* d_in, const int* in_sizes, int n_in,
                              void* d_out, int out_size, void* d_ws, size_t ws_size,
                              hipStream_t stream) {
    const float* probs  = (const float*)d_in[0];
    const int*   labels = (const int*)d_in[1];
    const int N = in_sizes[1];

    double* g_bri  = (double*)d_ws;
    float*  g_cnt  = (float*)((char*)d_ws + sizeof(double));
    float*  g_conf = g_cnt + NBINS;
    float*  g_acc  = g_conf + NBINS;

    // ws is re-poisoned to 0xAA before every launch — zero the accumulators.
    hipMemsetAsync(d_ws, 0, sizeof(double) + 3 * NBINS * sizeof(float), stream);

    // N=1e6 -> 15625 tile-iterations; 3125 blocks x exactly 5 iters, no tail.
    // 38 KB LDS -> 4 blocks/CU resident, ~102 KB staging in flight per CU.
    const int itersTotal = (N + RPI - 1) / RPI;
    const int blocks = itersTotal < 3125 ? itersTotal : 3125;
    hipLaunchKernelGGL(ece_rows, dim3(blocks), dim3(256), 0, stream,
                       probs, labels, N, g_bri, g_cnt, g_conf, g_acc);
    hipLaunchKernelGGL(ece_final, dim3(1), dim3(64), 0, stream,
                       g_bri, g_cnt, g_conf, g_acc, (float*)d_out, 1.f / (float)N);
}